// Round 1
// 345.815 us; speedup vs baseline: 1.0314x; 1.0314x over previous
//
#include <hip/hip_runtime.h>
#include <hip/hip_bf16.h>

typedef __hip_bfloat16 bf16;

#define B_   4
#define C_   32
#define DW_  64
#define H_   256
#define W_   256
#define P_   65536          // H_*W_
#define SRC_ 32             // source filter grid 32x32
#define PP_  66564          // padded plane 258*258

// ---- ws layout (float indices for the small stuff) ----
#define OW1    0            // 64*32
#define OB1    2048         // 64
#define OW3    2112         // 32*32
#define OB3    3136         // 32
#define OWS    3168         // 32*32 (sca)
#define OBS    4192         // 32
#define OW4    4224         // 64*32
#define OB4    6272         // 64
#define OW5    6336         // 32*32
#define OB5    7360         // 32
#define ON1W   7392
#define ON1B   7424
#define ON2W   7456
#define ON2B   7488
#define OBETA  7520
#define OGAMMA 7552
#define OSUMS  7584         // B_*C_ = 128
#define OSVEC  7712         // B_*C_ = 128
#define OFLAG  7900         // int flag: 0 = fp32 inputs, 1 = bf16 inputs
// byte offsets for big intermediates
#define CWF_BOFF 32768ull                        // cwf fp32: 4*64*9*1024*4 = 9437184 B
#define T1_BOFF  (CWF_BOFF + 9437184ull)         // t1 padded bf16: 256*66564*2 = 34080768 B
#define G_BOFF   (T1_BOFF + 34080768ull)         // g bf16: 16777216 B
// total ws ~= 60.3 MB

__device__ __forceinline__ bf16  f2b(float v){ return __float2bfloat16(v); }
__device__ __forceinline__ float bfu(unsigned short u){ return __uint_as_float(((unsigned int)u) << 16); }

template<typename T> __device__ __forceinline__ float ldf(const T* p);
template<> __device__ __forceinline__ float ldf<float>(const float* p){ return *p; }
template<> __device__ __forceinline__ float ldf<bf16>(const bf16* p){ return __bfloat162float(*p); }

template<typename T> __device__ __forceinline__ void stf(T* p, float v);
template<> __device__ __forceinline__ void stf<float>(float* p, float v){ *p = v; }
template<> __device__ __forceinline__ void stf<bf16>(bf16* p, float v){ *p = __float2bfloat16(v); }

template<typename T> struct dtag;
template<> struct dtag<float>{ static constexpr int v = 0; };
template<> struct dtag<bf16>{ static constexpr int v = 1; };

// ---------------- dtype detector (fp32 low-mantissa halves decode huge/NaN) ----------------
__global__ void k_detect(const unsigned short* __restrict__ raw, int* __restrict__ flag)
{
    int t = threadIdx.x;  // 64 threads
    int bad = 0;
    for (int k = 0; k < 8; ++k) {
        unsigned short u = raw[2 * (t + 64 * k)];
        float v = __uint_as_float(((unsigned int)u) << 16);
        if (!(fabsf(v) < 1e6f)) bad = 1;
    }
    int anybad = __any(bad);
    if (t == 0) *flag = anybad ? 0 : 1;
}

// ---------------- weights -> fp32 in ws, zero SCA sums ----------------
template<typename T>
__global__ void k_prep(const T* __restrict__ w1, const T* __restrict__ b1,
                       const T* __restrict__ w3, const T* __restrict__ b3,
                       const T* __restrict__ wsc, const T* __restrict__ bsc_,
                       const T* __restrict__ w4, const T* __restrict__ b4,
                       const T* __restrict__ w5, const T* __restrict__ b5,
                       const T* __restrict__ n1w, const T* __restrict__ n1b,
                       const T* __restrict__ n2w, const T* __restrict__ n2b,
                       const T* __restrict__ bet, const T* __restrict__ gam,
                       float* __restrict__ wsf, const int* __restrict__ flag)
{
    if (*flag != dtag<T>::v) return;
    int t = threadIdx.x;
    for (int i = t; i < 2048; i += 256) wsf[OW1 + i] = ldf<T>(w1 + i);
    for (int i = t; i < 64;   i += 256) wsf[OB1 + i] = ldf<T>(b1 + i);
    for (int i = t; i < 1024; i += 256) wsf[OW3 + i] = ldf<T>(w3 + i);
    for (int i = t; i < 32;   i += 256) wsf[OB3 + i] = ldf<T>(b3 + i);
    for (int i = t; i < 1024; i += 256) wsf[OWS + i] = ldf<T>(wsc + i);
    for (int i = t; i < 32;   i += 256) wsf[OBS + i] = ldf<T>(bsc_ + i);
    for (int i = t; i < 2048; i += 256) wsf[OW4 + i] = ldf<T>(w4 + i);
    for (int i = t; i < 64;   i += 256) wsf[OB4 + i] = ldf<T>(b4 + i);
    for (int i = t; i < 1024; i += 256) wsf[OW5 + i] = ldf<T>(w5 + i);
    for (int i = t; i < 32;   i += 256) wsf[OB5 + i] = ldf<T>(b5 + i);
    for (int i = t; i < 32;   i += 256) wsf[ON1W + i] = ldf<T>(n1w + i);
    for (int i = t; i < 32;   i += 256) wsf[ON1B + i] = ldf<T>(n1b + i);
    for (int i = t; i < 32;   i += 256) wsf[ON2W + i] = ldf<T>(n2w + i);
    for (int i = t; i < 32;   i += 256) wsf[ON2B + i] = ldf<T>(n2b + i);
    for (int i = t; i < 32;   i += 256) wsf[OBETA + i] = ldf<T>(bet + i);
    for (int i = t; i < 32;   i += 256) wsf[OGAMMA + i] = ldf<T>(gam + i);
    for (int i = t; i < 128;  i += 256) wsf[OSUMS + i] = 0.f;
}

// ---------------- cw2 -> fp32 copy (makes k_ddf dtype-free) ----------------
template<typename T>
__global__ void k_cwf(const T* __restrict__ cw, float* __restrict__ cwf,
                      const int* __restrict__ flag)
{
    if (*flag != dtag<T>::v) return;
    int i0 = blockIdx.x * 256 + threadIdx.x;
    const int n = B_ * DW_ * 9 * 1024;
    for (int i = i0; i < n; i += 262144) cwf[i] = ldf<T>(cw + i);
}

// ---------------- zero the padded borders of t1 ----------------
__global__ void k_zpad(unsigned short* __restrict__ t1u)
{
    unsigned short* pl = t1u + (size_t)blockIdx.x * PP_;   // 256 planes
    int t = threadIdx.x;
    for (int i = t; i < 258; i += 256) {
        pl[i] = 0;
        pl[257 * 258 + i] = 0;
    }
    // rows 1..256, cols 0 and 257
    pl[(t + 1) * 258] = 0;
    pl[(t + 1) * 258 + 257] = 0;
}

// ---------------- LayerNorm2d + conv1 (32->64), writes padded t1 ----------------
template<typename T>
__global__ __launch_bounds__(256) void k_ln1_conv1(const T* __restrict__ inp,
        const float* __restrict__ wsf, bf16* __restrict__ t1p,
        const int* __restrict__ flag)
{
    if (*flag != dtag<T>::v) return;
    int tid = blockIdx.x * 256 + threadIdx.x;   // 0 .. B*P-1
    int b = tid >> 16;
    int p = tid & 65535;
    int h = p >> 8, w = p & 255;
    const T* ip = inp + (size_t)b * C_ * P_ + p;
    float v[C_];
    float m = 0.f;
    #pragma unroll
    for (int ch = 0; ch < C_; ++ch) { v[ch] = ldf<T>(ip + ch * P_); m += v[ch]; }
    m *= (1.f / C_);
    float var = 0.f;
    #pragma unroll
    for (int ch = 0; ch < C_; ++ch) { float d = v[ch] - m; var += d * d; }
    var *= (1.f / C_);
    float inv = rsqrtf(var + 1e-6f);
    #pragma unroll
    for (int ch = 0; ch < C_; ++ch)
        v[ch] = (v[ch] - m) * inv * wsf[ON1W + ch] + wsf[ON1B + ch];

    bf16* op = t1p + (size_t)(b * DW_) * PP_ + (h + 1) * 258 + (w + 1);
    #pragma unroll 4
    for (int o = 0; o < DW_; ++o) {
        float acc = wsf[OB1 + o];
        #pragma unroll
        for (int ch = 0; ch < C_; ++ch) acc += v[ch] * wsf[OW1 + o * C_ + ch];
        op[(size_t)o * PP_] = f2b(acc);
    }
}

// ------ DDF v3: corner-sum restructure ------
// out[pix] = sum_tap p[tap] * bilerp(W[tap]) is re-associated as
// out[pix] = sum_{2x2 corners} bw[corner] * (sum_tap p[tap]*W[tap,corner]).
// Each lane's bilinear support is exactly a 2x2 window of the staged 4x4
// corner grid, at a per-lane-constant position -> 4 FMA + 4 LDS dwords per
// (tap,plane) instead of 12 FMA + 12 LDS dwords. LDS reads are base+imm
// offsets {wo,wo+1,wo+4,wo+5} -> 2x ds_read2_b32 per tap per plane, 4
// distinct addresses per wave (broadcast, conflict-free).
__global__ __launch_bounds__(256, 4) void k_ddf(const unsigned short* __restrict__ t1u,
        const float* __restrict__ cwf, bf16* __restrict__ g)
{
    __shared__ float V4[9216];   // [ch*9+tap][4 rows][4 cols] fp32, 36864 B

    int bid = blockIdx.x;
    int b = bid >> 8;
    int tb = bid & 255;
    int bch = (tb >> 4) * 2;     // base cell row (2x2 cells per block)
    int bcw = (tb & 15) * 2;

    // --- cooperative staging of the 4x4 filter-corner region for all 576 (ch,tap) ---
    {
        const float* cb = cwf + (size_t)b * (DW_ * 9 * 1024);
        int rof[4], cof[4];
        #pragma unroll
        for (int k = 0; k < 4; ++k) {
            int rr = bch - 1 + k; rr = rr < 0 ? 0 : (rr > 31 ? 31 : rr);
            int cc = bcw - 1 + k; cc = cc < 0 ? 0 : (cc > 31 ? 31 : cc);
            rof[k] = rr * SRC_; cof[k] = cc;
        }
        for (int it = 0; it < 36; ++it) {
            int idx = it * 256 + threadIdx.x;        // 0..9215
            int cc = idx & 3, rr = (idx >> 2) & 3, pt = idx >> 4;
            V4[idx] = cb[pt * 1024 + rof[rr] + cof[cc]];
        }
    }
    __syncthreads();

    int wid = threadIdx.x >> 6, lane = threadIdx.x & 63;
    int rbase = wid >> 1, cbase = wid & 1;
    int cellh = bch + rbase, cellw = bcw + cbase;
    int r = lane >> 3, c = lane & 7;
    int h = cellh * 8 + r, w = cellw * 8 + c;

    // half-pixel-center bilinear: pixel r interpolates source rows
    // (cellh-1+rsel, cellh+rsel) with fraction fh; same for columns.
    int rsel = r >> 2, csel = c >> 2;
    float fh = rsel ? ((float)r * 0.125f - 0.4375f) : ((float)r * 0.125f + 0.5625f);
    float fw = csel ? ((float)c * 0.125f - 0.4375f) : ((float)c * 0.125f + 0.5625f);
    float bw00 = (1.f - fh) * (1.f - fw);
    float bw01 = (1.f - fh) * fw;
    float bw10 = fh * (1.f - fw);
    float bw11 = fh * fw;

    // per-lane 2x2 window position inside the staged 4x4 grid
    int lbase = (rbase + rsel) * 4 + (cbase + csel);   // float offset within 16-float tap block

    int hw0 = h * 258 + w;    // padded base: tap (i,j) at hw0 + i*258 + j
    bf16* gp = g + (size_t)(b * C_) * P_ + h * 256 + w;
    const unsigned short* plb = t1u + (size_t)b * DW_ * PP_ + hw0;

    for (int cp = 0; cp < C_; ++cp) {
        const unsigned short* pl1 = plb + (size_t)cp * PP_;
        const unsigned short* pl2 = pl1 + (size_t)C_ * PP_;
        const float* q1 = V4 + cp * 144 + lbase;       // 9 taps * 16 floats per (ch)
        const float* q2 = q1 + 32 * 144;
        float S00a = 0.f, S01a = 0.f, S10a = 0.f, S11a = 0.f;
        float S00b = 0.f, S01b = 0.f, S10b = 0.f, S11b = 0.f;
        #pragma unroll
        for (int i = 0; i < 3; ++i) {
            #pragma unroll
            for (int j = 0; j < 3; ++j) {
                int po = i * 258 + j;
                int wo = (i * 3 + j) * 16;
                float p1 = bfu(pl1[po]);
                float p2 = bfu(pl2[po]);
                S00a += p1 * q1[wo + 0];
                S01a += p1 * q1[wo + 1];
                S10a += p1 * q1[wo + 4];
                S11a += p1 * q1[wo + 5];
                S00b += p2 * q2[wo + 0];
                S01b += p2 * q2[wo + 1];
                S10b += p2 * q2[wo + 4];
                S11b += p2 * q2[wo + 5];
            }
        }
        float acc1 = bw00 * S00a + bw01 * S01a + bw10 * S10a + bw11 * S11a;
        float acc2 = bw00 * S00b + bw01 * S01b + bw10 * S10b + bw11 * S11b;
        gp[cp * P_] = f2b(acc1 * acc2);
    }
}

// ---------------- per-(b,ch) sums of g for SCA ----------------
__global__ void k_rsum(const unsigned int* __restrict__ gu, float* __restrict__ sums)
{
    __shared__ float red[4];
    int blk = blockIdx.x;            // 512 blocks
    int b = blk >> 7, ch = (blk >> 2) & 31, q = blk & 3;
    int base32 = (b * 32 + ch) * 32768 + q * 8192;   // u32 index
    int t = threadIdx.x;
    float s = 0.f;
    for (int it = 0; it < 32; ++it) {
        unsigned int u = gu[base32 + it * 256 + t];
        s += __uint_as_float(u << 16);
        s += __uint_as_float(u & 0xFFFF0000u);
    }
    #pragma unroll
    for (int off = 32; off >= 1; off >>= 1) s += __shfl_xor(s, off, 64);
    int lane = t & 63, wid = t >> 6;
    if (lane == 0) red[wid] = s;
    __syncthreads();
    if (t == 0) atomicAdd(&sums[b * 32 + ch], red[0] + red[1] + red[2] + red[3]);
}

// ---------------- SCA vector: s = sca_w @ mean + sca_b ----------------
__global__ void k_sca(float* __restrict__ wsf)
{
    int t = threadIdx.x;            // 128 threads
    int b = t >> 5, o = t & 31;
    float acc = wsf[OBS + o];
    #pragma unroll
    for (int ch = 0; ch < C_; ++ch)
        acc += wsf[OWS + o * C_ + ch] * (wsf[OSUMS + b * C_ + ch] * (1.f / (float)P_));
    wsf[OSVEC + b * C_ + o] = acc;
}

// ------- tail: scale, conv3, +beta residual, LN2, conv4, gate, conv5, out -------
template<typename T>
__global__ __launch_bounds__(256) void k_tail(const T* __restrict__ inp,
        const bf16* __restrict__ g, const float* __restrict__ wsf,
        T* __restrict__ out, const int* __restrict__ flag)
{
    if (*flag != dtag<T>::v) return;
    int tid = blockIdx.x * 256 + threadIdx.x;
    int b = tid >> 16;
    int p = tid & 65535;
    const bf16* gp = g + (size_t)b * C_ * P_ + p;
    const T* ip = inp + (size_t)b * C_ * P_ + p;

    float x[C_];
    #pragma unroll
    for (int ch = 0; ch < C_; ++ch)
        x[ch] = __bfloat162float(gp[ch * P_]) * wsf[OSVEC + b * C_ + ch];

    float y[C_];
    #pragma unroll 4
    for (int o = 0; o < C_; ++o) {
        float acc = wsf[OB3 + o];
        #pragma unroll
        for (int ch = 0; ch < C_; ++ch) acc += x[ch] * wsf[OW3 + o * C_ + ch];
        y[o] = ldf<T>(ip + o * P_) + acc * wsf[OBETA + o];
    }

    float m = 0.f;
    #pragma unroll
    for (int ch = 0; ch < C_; ++ch) m += y[ch];
    m *= (1.f / C_);
    float var = 0.f;
    #pragma unroll
    for (int ch = 0; ch < C_; ++ch) { float d = y[ch] - m; var += d * d; }
    var *= (1.f / C_);
    float inv = rsqrtf(var + 1e-6f);
    float yn[C_];
    #pragma unroll
    for (int ch = 0; ch < C_; ++ch)
        yn[ch] = (y[ch] - m) * inv * wsf[ON2W + ch] + wsf[ON2B + ch];

    float u[C_];
    #pragma unroll 2
    for (int o = 0; o < C_; ++o) {
        float a = wsf[OB4 + o], bb = wsf[OB4 + 32 + o];
        #pragma unroll
        for (int ch = 0; ch < C_; ++ch) {
            a  += yn[ch] * wsf[OW4 + o * C_ + ch];
            bb += yn[ch] * wsf[OW4 + (o + 32) * C_ + ch];
        }
        u[o] = a * bb;
    }

    T* op = out + (size_t)b * C_ * P_ + p;
    #pragma unroll 4
    for (int o = 0; o < C_; ++o) {
        float acc = wsf[OB5 + o];
        #pragma unroll
        for (int ch = 0; ch < C_; ++ch) acc += u[ch] * wsf[OW5 + o * C_ + ch];
        stf<T>(op + o * P_, y[o] + acc * wsf[OGAMMA + o]);
    }
}

extern "C" void kernel_launch(void* const* d_in, const int* in_sizes, int n_in,
                              void* d_out, int out_size, void* d_ws, size_t ws_size,
                              hipStream_t stream)
{
    float* wsf = (float*)d_ws;
    char* wsb = (char*)d_ws;
    float* cwf = (float*)(wsb + CWF_BOFF);
    bf16* t1p = (bf16*)(wsb + T1_BOFF);
    bf16* g   = (bf16*)(wsb + G_BOFF);
    int* flag = (int*)(wsf + OFLAG);

    k_detect<<<1, 64, 0, stream>>>((const unsigned short*)d_in[0], flag);

    int nblk = (B_ * P_) / 256;   // 1024

    // prep + cw conversion, both dtype variants (dead one exits on flag)
    k_prep<float><<<1, 256, 0, stream>>>(
        (const float*)d_in[2], (const float*)d_in[3], (const float*)d_in[4],
        (const float*)d_in[5], (const float*)d_in[6], (const float*)d_in[7],
        (const float*)d_in[8], (const float*)d_in[9], (const float*)d_in[10],
        (const float*)d_in[11], (const float*)d_in[12], (const float*)d_in[13],
        (const float*)d_in[14], (const float*)d_in[15], (const float*)d_in[16],
        (const float*)d_in[17], wsf, flag);
    k_prep<bf16><<<1, 256, 0, stream>>>(
        (const bf16*)d_in[2], (const bf16*)d_in[3], (const bf16*)d_in[4],
        (const bf16*)d_in[5], (const bf16*)d_in[6], (const bf16*)d_in[7],
        (const bf16*)d_in[8], (const bf16*)d_in[9], (const bf16*)d_in[10],
        (const bf16*)d_in[11], (const bf16*)d_in[12], (const bf16*)d_in[13],
        (const bf16*)d_in[14], (const bf16*)d_in[15], (const bf16*)d_in[16],
        (const bf16*)d_in[17], wsf, flag);
    k_cwf<float><<<1024, 256, 0, stream>>>((const float*)d_in[1], cwf, flag);
    k_cwf<bf16><<<1024, 256, 0, stream>>>((const bf16*)d_in[1], cwf, flag);

    k_zpad<<<256, 256, 0, stream>>>((unsigned short*)t1p);

    k_ln1_conv1<float><<<nblk, 256, 0, stream>>>((const float*)d_in[0], wsf, t1p, flag);
    k_ln1_conv1<bf16><<<nblk, 256, 0, stream>>>((const bf16*)d_in[0], wsf, t1p, flag);

    k_ddf<<<1024, 256, 0, stream>>>((const unsigned short*)t1p, cwf, g);

    k_rsum<<<512, 256, 0, stream>>>((const unsigned int*)g, wsf + OSUMS);
    k_sca<<<1, 128, 0, stream>>>(wsf);

    k_tail<float><<<nblk, 256, 0, stream>>>((const float*)d_in[0], g, wsf,
                                            (float*)d_out, flag);
    k_tail<bf16><<<nblk, 256, 0, stream>>>((const bf16*)d_in[0], g, wsf,
                                           (bf16*)d_out, flag);
}

// Round 2
// 312.686 us; speedup vs baseline: 1.1407x; 1.1059x over previous
//
#include <hip/hip_runtime.h>
#include <hip/hip_bf16.h>

typedef __hip_bfloat16 bf16;
typedef __attribute__((ext_vector_type(8))) unsigned short u16x8;

#define B_   4
#define C_   32
#define DW_  64
#define H_   256
#define W_   256
#define P_   65536          // H_*W_
#define SRC_ 32             // source filter grid 32x32
#define TRS_ 272            // t1 padded row stride in shorts (544 B = 34*16, keeps 16B align)
#define TPL_ 70176          // padded plane shorts: 258 rows * 272

// ---- ws layout (float indices for the small stuff) ----
#define OW1    0            // 64*32
#define OB1    2048         // 64
#define OW3    2112         // 32*32
#define OB3    3136         // 32
#define OWS    3168         // 32*32 (sca)
#define OBS    4192         // 32
#define OW4    4224         // 64*32
#define OB4    6272         // 64
#define OW5    6336         // 32*32
#define OB5    7360         // 32
#define ON1W   7392
#define ON1B   7424
#define ON2W   7456
#define ON2B   7488
#define OBETA  7520
#define OGAMMA 7552
#define OSUMS  7584         // B_*C_ = 128
#define OSVEC  7712         // B_*C_ = 128
#define OFLAG  7900         // int flag: 0 = fp32 inputs, 1 = bf16 inputs
// byte offsets for big intermediates
#define CWF_BOFF 32768ull                        // cwf fp32: 4*64*9*1024*4 = 9437184 B
#define T1_BOFF  (CWF_BOFF + 9437184ull)         // t1 padded bf16: 256*70176*2 = 35930112 B
#define G_BOFF   (T1_BOFF + 35930112ull)         // g bf16: 16777216 B
// total ws ~= 62.2 MB

__device__ __forceinline__ bf16  f2b(float v){ return __float2bfloat16(v); }
__device__ __forceinline__ float bfu(unsigned short u){ return __uint_as_float(((unsigned int)u) << 16); }

template<typename T> __device__ __forceinline__ float ldf(const T* p);
template<> __device__ __forceinline__ float ldf<float>(const float* p){ return *p; }
template<> __device__ __forceinline__ float ldf<bf16>(const bf16* p){ return __bfloat162float(*p); }

template<typename T> __device__ __forceinline__ void stf(T* p, float v);
template<> __device__ __forceinline__ void stf<float>(float* p, float v){ *p = v; }
template<> __device__ __forceinline__ void stf<bf16>(bf16* p, float v){ *p = __float2bfloat16(v); }

template<typename T> struct dtag;
template<> struct dtag<float>{ static constexpr int v = 0; };
template<> struct dtag<bf16>{ static constexpr int v = 1; };

// ---------------- dtype detector (fp32 low-mantissa halves decode huge/NaN) ----------------
__global__ void k_detect(const unsigned short* __restrict__ raw, int* __restrict__ flag)
{
    int t = threadIdx.x;  // 64 threads
    int bad = 0;
    for (int k = 0; k < 8; ++k) {
        unsigned short u = raw[2 * (t + 64 * k)];
        float v = __uint_as_float(((unsigned int)u) << 16);
        if (!(fabsf(v) < 1e6f)) bad = 1;
    }
    int anybad = __any(bad);
    if (t == 0) *flag = anybad ? 0 : 1;
}

// ---------------- weights -> fp32 in ws, zero SCA sums ----------------
template<typename T>
__global__ void k_prep(const T* __restrict__ w1, const T* __restrict__ b1,
                       const T* __restrict__ w3, const T* __restrict__ b3,
                       const T* __restrict__ wsc, const T* __restrict__ bsc_,
                       const T* __restrict__ w4, const T* __restrict__ b4,
                       const T* __restrict__ w5, const T* __restrict__ b5,
                       const T* __restrict__ n1w, const T* __restrict__ n1b,
                       const T* __restrict__ n2w, const T* __restrict__ n2b,
                       const T* __restrict__ bet, const T* __restrict__ gam,
                       float* __restrict__ wsf, const int* __restrict__ flag)
{
    if (*flag != dtag<T>::v) return;
    int t = threadIdx.x;
    for (int i = t; i < 2048; i += 256) wsf[OW1 + i] = ldf<T>(w1 + i);
    for (int i = t; i < 64;   i += 256) wsf[OB1 + i] = ldf<T>(b1 + i);
    for (int i = t; i < 1024; i += 256) wsf[OW3 + i] = ldf<T>(w3 + i);
    for (int i = t; i < 32;   i += 256) wsf[OB3 + i] = ldf<T>(b3 + i);
    for (int i = t; i < 1024; i += 256) wsf[OWS + i] = ldf<T>(wsc + i);
    for (int i = t; i < 32;   i += 256) wsf[OBS + i] = ldf<T>(bsc_ + i);
    for (int i = t; i < 2048; i += 256) wsf[OW4 + i] = ldf<T>(w4 + i);
    for (int i = t; i < 64;   i += 256) wsf[OB4 + i] = ldf<T>(b4 + i);
    for (int i = t; i < 1024; i += 256) wsf[OW5 + i] = ldf<T>(w5 + i);
    for (int i = t; i < 32;   i += 256) wsf[OB5 + i] = ldf<T>(b5 + i);
    for (int i = t; i < 32;   i += 256) wsf[ON1W + i] = ldf<T>(n1w + i);
    for (int i = t; i < 32;   i += 256) wsf[ON1B + i] = ldf<T>(n1b + i);
    for (int i = t; i < 32;   i += 256) wsf[ON2W + i] = ldf<T>(n2w + i);
    for (int i = t; i < 32;   i += 256) wsf[ON2B + i] = ldf<T>(n2b + i);
    for (int i = t; i < 32;   i += 256) wsf[OBETA + i] = ldf<T>(bet + i);
    for (int i = t; i < 32;   i += 256) wsf[OGAMMA + i] = ldf<T>(gam + i);
    for (int i = t; i < 128;  i += 256) wsf[OSUMS + i] = 0.f;
}

// ---------------- cw2 -> fp32 copy (vectorized, single kernel, flag branch) ----------------
// n = 4*64*9*1024 floats = 2359296 -> 589824 float4s; grid 2304*256 exact.
__global__ void k_cwf(const void* __restrict__ cw, float4* __restrict__ cwf4,
                      const int* __restrict__ flag)
{
    int i4 = blockIdx.x * 256 + threadIdx.x;
    if (*flag == 0) {
        cwf4[i4] = ((const float4*)cw)[i4];
    } else {
        const ushort4* p = (const ushort4*)cw;
        ushort4 v = p[i4];
        cwf4[i4] = make_float4(bfu(v.x), bfu(v.y), bfu(v.z), bfu(v.w));
    }
}

// ---------------- zero the padded borders of t1 (stride-272 layout) ----------------
__global__ void k_zpad(unsigned short* __restrict__ t1u)
{
    unsigned short* pl = t1u + (size_t)blockIdx.x * TPL_;   // 256 planes
    int t = threadIdx.x;
    for (int i = t; i < 258; i += 256) {
        pl[i] = 0;                       // padded row 0, cols 0..257
        pl[257 * TRS_ + i] = 0;          // padded row 257
    }
    pl[(t + 1) * TRS_] = 0;              // col 0, rows 1..256
    pl[(t + 1) * TRS_ + 257] = 0;        // col 257
}

// ---------------- LayerNorm2d + conv1 (32->64), writes padded t1 ----------------
template<typename T>
__device__ __forceinline__ void ln1_body(const T* __restrict__ inp,
        const float* __restrict__ wsf, bf16* __restrict__ t1p)
{
    int tid = blockIdx.x * 256 + threadIdx.x;   // 0 .. B*P-1
    int b = tid >> 16;
    int p = tid & 65535;
    int h = p >> 8, w = p & 255;
    const T* ip = inp + (size_t)b * C_ * P_ + p;
    float v[C_];
    float m = 0.f;
    #pragma unroll
    for (int ch = 0; ch < C_; ++ch) { v[ch] = ldf<T>(ip + ch * P_); m += v[ch]; }
    m *= (1.f / C_);
    float var = 0.f;
    #pragma unroll
    for (int ch = 0; ch < C_; ++ch) { float d = v[ch] - m; var += d * d; }
    var *= (1.f / C_);
    float inv = rsqrtf(var + 1e-6f);
    #pragma unroll
    for (int ch = 0; ch < C_; ++ch)
        v[ch] = (v[ch] - m) * inv * wsf[ON1W + ch] + wsf[ON1B + ch];

    bf16* op = t1p + (size_t)(b * DW_) * TPL_ + (h + 1) * TRS_ + (w + 1);
    #pragma unroll 4
    for (int o = 0; o < DW_; ++o) {
        float acc = wsf[OB1 + o];
        #pragma unroll
        for (int ch = 0; ch < C_; ++ch) acc += v[ch] * wsf[OW1 + o * C_ + ch];
        op[(size_t)o * TPL_] = f2b(acc);
    }
}

__global__ __launch_bounds__(256) void k_ln1_conv1(const void* __restrict__ inp,
        const float* __restrict__ wsf, bf16* __restrict__ t1p,
        const int* __restrict__ flag)
{
    if (*flag == 0) ln1_body<float>((const float*)inp, wsf, t1p);
    else            ln1_body<bf16>((const bf16*)inp, wsf, t1p);
}

// ------ DDF v4: 8 px per lane, vectorized t1 row loads, per-cp LDS filter slice ------
// Lane owns one 8-px cell row. Per (cp, plane, tap-row): dwordx4 + dword covers the
// 10 needed t1 pixels. Corner-sum form (4 corners x 9 taps per px); the 6 filter
// corner values per tap are shared by the lane's 8 px. Block = 4x4 cells (32x64 px)
// x 4 cp; stages 6x10 corner grid for its 8 channels (17.3 KB LDS).
#define G_ 4
__global__ __launch_bounds__(256, 4) void k_ddf(const unsigned short* __restrict__ t1u,
        const float* __restrict__ cwf, bf16* __restrict__ g, float* __restrict__ sums)
{
    __shared__ float CWs[4320];   // [2G ch][9 tap][6 rows][10 cols] = 17280 B

    int bid = blockIdx.x;         // 1024
    int tile = bid & 31;          // 8 row-tiles x 4 col-tiles
    int cg  = (bid >> 5) & 7;     // 8 cp-groups of G_=4
    int b   = bid >> 8;           // 4
    int th = tile >> 2, tw = tile & 3;
    int cellh0 = th * 4;          // 4 cell rows per block
    int cellw0 = tw * 8;          // 8 cell cols per block
    int cp0 = cg * G_;

    // --- stage corner slice: rows cellh0-1..+4, cols cellw0-1..+8, ch {cp0..+3, +32...} ---
    {
        const float* cb = cwf + (size_t)b * (DW_ * 9 * 1024);
        for (int it = 0; it < 17; ++it) {
            int idx = it * 256 + threadIdx.x;
            if (idx < 4320) {
                int cc  = idx % 10;
                int t2  = idx / 10;
                int rr  = t2 % 6;
                int t3  = t2 / 6;
                int tap = t3 % 9;
                int chl = t3 / 9;
                int ch = (chl < G_) ? (cp0 + chl) : (C_ + cp0 + chl - G_);
                int cr = cellh0 - 1 + rr; cr = cr < 0 ? 0 : (cr > 31 ? 31 : cr);
                int cw = cellw0 - 1 + cc; cw = cw < 0 ? 0 : (cw > 31 ? 31 : cw);
                CWs[idx] = cb[ch * 9216 + tap * 1024 + cr * SRC_ + cw];
            }
        }
    }
    __syncthreads();

    int lane = threadIdx.x & 63, wid = threadIdx.x >> 6;
    int k = lane >> 3, r = lane & 7;
    int cellh = cellh0 + wid;
    int h = cellh * 8 + r;
    int w = (cellw0 + k) * 8;

    int rsel = r >> 2;
    float fh = rsel ? ((float)r * 0.125f - 0.4375f) : ((float)r * 0.125f + 0.5625f);
    float gh = 1.f - fh;
    int rr0k = (wid + rsel) * 10 + k;   // LDS offset of lane's corner window

    // padded t1: real (h+i-1, w+j-1) lives at padded ((h+i), (w+j)); row base 16B-aligned
    const unsigned short* tb = t1u + (size_t)(b * DW_) * TPL_ + (size_t)h * TRS_ + w;
    bf16* gp = g + (size_t)(b * C_) * P_ + h * 256 + w;

    for (int l = 0; l < G_; ++l) {
        int cp = cp0 + l;
        const unsigned short* pl1 = tb + (size_t)cp * TPL_;
        const unsigned short* pl2 = pl1 + (size_t)C_ * TPL_;
        const float* q1 = CWs + l * 540;
        const float* q2 = CWs + (G_ + l) * 540;

        float acc1[8], acc2[8];
        #pragma unroll
        for (int pass = 0; pass < 2; ++pass) {
            const unsigned short* pl = pass ? pl2 : pl1;
            const float* q = pass ? q2 : q1;
            float* acc = pass ? acc2 : acc1;

            u16x8 v8[3];
            unsigned int ve[3];
            #pragma unroll
            for (int i = 0; i < 3; ++i) {
                const unsigned short* rp = pl + i * TRS_;
                v8[i] = *(const u16x8*)rp;              // shorts [w .. w+7], 16B aligned
                ve[i] = *(const unsigned int*)(rp + 8); // shorts [w+8, w+9]
            }
            float S00[8], S01[8], S10[8], S11[8];
            #pragma unroll
            for (int c = 0; c < 8; ++c) { S00[c]=0.f; S01[c]=0.f; S10[c]=0.f; S11[c]=0.f; }
            #pragma unroll
            for (int i = 0; i < 3; ++i) {
                float p[10];
                #pragma unroll
                for (int j = 0; j < 8; ++j) p[j] = bfu((unsigned short)v8[i][j]);
                p[8] = bfu((unsigned short)(ve[i] & 0xFFFFu));
                p[9] = bfu((unsigned short)(ve[i] >> 16));
                #pragma unroll
                for (int j = 0; j < 3; ++j) {
                    const float* qb = q + (i * 3 + j) * 60 + rr0k;
                    float w00 = qb[0],  w01 = qb[1],  w02 = qb[2];
                    float w10 = qb[10], w11 = qb[11], w12 = qb[12];
                    #pragma unroll
                    for (int c = 0; c < 8; ++c) {
                        float pv = p[c + j];
                        S00[c] += pv * ((c < 4) ? w00 : w01);
                        S01[c] += pv * ((c < 4) ? w01 : w02);
                        S10[c] += pv * ((c < 4) ? w10 : w11);
                        S11[c] += pv * ((c < 4) ? w11 : w12);
                    }
                }
            }
            const float fwt[8] = {0.5625f, 0.6875f, 0.8125f, 0.9375f,
                                  0.0625f, 0.1875f, 0.3125f, 0.4375f};
            #pragma unroll
            for (int c = 0; c < 8; ++c) {
                float fw = fwt[c], gw = 1.f - fw;
                acc[c] = gh * (gw * S00[c] + fw * S01[c]) + fh * (gw * S10[c] + fw * S11[c]);
            }
        }

        // gate, pack 8 bf16, store; accumulate SCA partial sum
        u16x8 ov;
        float s = 0.f;
        #pragma unroll
        for (int c = 0; c < 8; ++c) {
            float gv = acc1[c] * acc2[c];
            s += gv;
            bf16 bv = f2b(gv);
            ov[c] = *reinterpret_cast<unsigned short*>(&bv);
        }
        *(u16x8*)(gp + (size_t)cp * P_) = ov;

        #pragma unroll
        for (int off = 32; off >= 1; off >>= 1) s += __shfl_xor(s, off, 64);
        if (lane == 0) atomicAdd(&sums[b * C_ + cp], s);
    }
}

// ---------------- SCA vector: s = sca_w @ mean + sca_b ----------------
__global__ void k_sca(float* __restrict__ wsf)
{
    int t = threadIdx.x;            // 128 threads
    int b = t >> 5, o = t & 31;
    float acc = wsf[OBS + o];
    #pragma unroll
    for (int ch = 0; ch < C_; ++ch)
        acc += wsf[OWS + o * C_ + ch] * (wsf[OSUMS + b * C_ + ch] * (1.f / (float)P_));
    wsf[OSVEC + b * C_ + o] = acc;
}

// ------- tail: scale, conv3, +beta residual, LN2, conv4, gate, conv5, out -------
template<typename T>
__device__ __forceinline__ void tail_body(const T* __restrict__ inp,
        const bf16* __restrict__ g, const float* __restrict__ wsf,
        T* __restrict__ out)
{
    int tid = blockIdx.x * 256 + threadIdx.x;
    int b = tid >> 16;
    int p = tid & 65535;
    const bf16* gp = g + (size_t)b * C_ * P_ + p;
    const T* ip = inp + (size_t)b * C_ * P_ + p;

    float x[C_];
    #pragma unroll
    for (int ch = 0; ch < C_; ++ch)
        x[ch] = __bfloat162float(gp[ch * P_]) * wsf[OSVEC + b * C_ + ch];

    float y[C_];
    #pragma unroll 4
    for (int o = 0; o < C_; ++o) {
        float acc = wsf[OB3 + o];
        #pragma unroll
        for (int ch = 0; ch < C_; ++ch) acc += x[ch] * wsf[OW3 + o * C_ + ch];
        y[o] = ldf<T>(ip + o * P_) + acc * wsf[OBETA + o];
    }

    float m = 0.f;
    #pragma unroll
    for (int ch = 0; ch < C_; ++ch) m += y[ch];
    m *= (1.f / C_);
    float var = 0.f;
    #pragma unroll
    for (int ch = 0; ch < C_; ++ch) { float d = y[ch] - m; var += d * d; }
    var *= (1.f / C_);
    float inv = rsqrtf(var + 1e-6f);
    float yn[C_];
    #pragma unroll
    for (int ch = 0; ch < C_; ++ch)
        yn[ch] = (y[ch] - m) * inv * wsf[ON2W + ch] + wsf[ON2B + ch];

    float u[C_];
    #pragma unroll 2
    for (int o = 0; o < C_; ++o) {
        float a = wsf[OB4 + o], bb = wsf[OB4 + 32 + o];
        #pragma unroll
        for (int ch = 0; ch < C_; ++ch) {
            a  += yn[ch] * wsf[OW4 + o * C_ + ch];
            bb += yn[ch] * wsf[OW4 + (o + 32) * C_ + ch];
        }
        u[o] = a * bb;
    }

    T* op = out + (size_t)b * C_ * P_ + p;
    #pragma unroll 4
    for (int o = 0; o < C_; ++o) {
        float acc = wsf[OB5 + o];
        #pragma unroll
        for (int ch = 0; ch < C_; ++ch) acc += u[ch] * wsf[OW5 + o * C_ + ch];
        stf<T>(op + o * P_, y[o] + acc * wsf[OGAMMA + o]);
    }
}

__global__ __launch_bounds__(256) void k_tail(const void* __restrict__ inp,
        const bf16* __restrict__ g, const float* __restrict__ wsf,
        void* __restrict__ out, const int* __restrict__ flag)
{
    if (*flag == 0) tail_body<float>((const float*)inp, g, wsf, (float*)out);
    else            tail_body<bf16>((const bf16*)inp, g, wsf, (bf16*)out);
}

extern "C" void kernel_launch(void* const* d_in, const int* in_sizes, int n_in,
                              void* d_out, int out_size, void* d_ws, size_t ws_size,
                              hipStream_t stream)
{
    float* wsf = (float*)d_ws;
    char* wsb = (char*)d_ws;
    float* cwf = (float*)(wsb + CWF_BOFF);
    bf16* t1p = (bf16*)(wsb + T1_BOFF);
    bf16* g   = (bf16*)(wsb + G_BOFF);
    int* flag = (int*)(wsf + OFLAG);

    k_detect<<<1, 64, 0, stream>>>((const unsigned short*)d_in[0], flag);

    int nblk = (B_ * P_) / 256;   // 1024

    // prep: both dtype variants (1 block each; dead one exits on flag)
    k_prep<float><<<1, 256, 0, stream>>>(
        (const float*)d_in[2], (const float*)d_in[3], (const float*)d_in[4],
        (const float*)d_in[5], (const float*)d_in[6], (const float*)d_in[7],
        (const float*)d_in[8], (const float*)d_in[9], (const float*)d_in[10],
        (const float*)d_in[11], (const float*)d_in[12], (const float*)d_in[13],
        (const float*)d_in[14], (const float*)d_in[15], (const float*)d_in[16],
        (const float*)d_in[17], wsf, flag);
    k_prep<bf16><<<1, 256, 0, stream>>>(
        (const bf16*)d_in[2], (const bf16*)d_in[3], (const bf16*)d_in[4],
        (const bf16*)d_in[5], (const bf16*)d_in[6], (const bf16*)d_in[7],
        (const bf16*)d_in[8], (const bf16*)d_in[9], (const bf16*)d_in[10],
        (const bf16*)d_in[11], (const bf16*)d_in[12], (const bf16*)d_in[13],
        (const bf16*)d_in[14], (const bf16*)d_in[15], (const bf16*)d_in[16],
        (const bf16*)d_in[17], wsf, flag);

    k_cwf<<<2304, 256, 0, stream>>>(d_in[1], (float4*)cwf, flag);

    k_zpad<<<256, 256, 0, stream>>>((unsigned short*)t1p);

    k_ln1_conv1<<<nblk, 256, 0, stream>>>(d_in[0], wsf, t1p, flag);

    k_ddf<<<1024, 256, 0, stream>>>((const unsigned short*)t1p, cwf, g, wsf + OSUMS);

    k_sca<<<1, 128, 0, stream>>>(wsf);

    k_tail<<<nblk, 256, 0, stream>>>(d_in[0], g, wsf, d_out, flag);
}

// Round 3
// 266.011 us; speedup vs baseline: 1.3409x; 1.1755x over previous
//
#include <hip/hip_runtime.h>
#include <hip/hip_bf16.h>

typedef __hip_bfloat16 bf16;
typedef __attribute__((ext_vector_type(8))) unsigned short u16x8;
typedef __attribute__((ext_vector_type(8))) short s16x8;
typedef __attribute__((ext_vector_type(4))) float f32x4;
typedef __attribute__((ext_vector_type(4))) unsigned short us16x4;

#define B_   4
#define C_   32
#define DW_  64
#define H_   256
#define W_   256
#define P_   65536          // H_*W_
#define SRC_ 32             // source filter grid 32x32
#define TRS_ 272            // t1 padded row stride in shorts (544 B = 34*16, keeps 16B align)
#define TPL_ 70176          // padded plane shorts: 258 rows * 272

// ---- ws layout (float indices for the small stuff) ----
#define OW1    0            // 64*32
#define OB1    2048         // 64
#define OW3    2112         // 32*32
#define OB3    3136         // 32
#define OWS    3168         // 32*32 (sca)
#define OBS    4192         // 32
#define OW4    4224         // 64*32
#define OB4    6272         // 64
#define OW5    6336         // 32*32
#define OB5    7360         // 32
#define ON1W   7392
#define ON1B   7424
#define ON2W   7456
#define ON2B   7488
#define OBETA  7520
#define OGAMMA 7552
#define OSUMS  7584         // B_*C_ = 128
#define OSVEC  7712         // B_*C_ = 128
#define OFLAG  7900         // int flag: 0 = fp32 inputs, 1 = bf16 inputs
// byte offsets for big intermediates
#define CWF_BOFF 32768ull                        // cwf fp32: 4*64*9*1024*4 = 9437184 B
#define T1_BOFF  (CWF_BOFF + 9437184ull)         // t1 padded bf16: 256*70176*2 = 35930112 B
#define G_BOFF   (T1_BOFF + 35930112ull)         // g bf16: 16777216 B
// total ws ~= 62.2 MB

__device__ __forceinline__ bf16  f2b(float v){ return __float2bfloat16(v); }
__device__ __forceinline__ float bfu(unsigned short u){ return __uint_as_float(((unsigned int)u) << 16); }
__device__ __forceinline__ unsigned short fbits(float v){
    bf16 b = __float2bfloat16(v);
    return *reinterpret_cast<unsigned short*>(&b);
}

template<typename T> __device__ __forceinline__ float ldf(const T* p);
template<> __device__ __forceinline__ float ldf<float>(const float* p){ return *p; }
template<> __device__ __forceinline__ float ldf<bf16>(const bf16* p){ return __bfloat162float(*p); }

template<typename T> __device__ __forceinline__ void stf(T* p, float v);
template<> __device__ __forceinline__ void stf<float>(float* p, float v){ *p = v; }
template<> __device__ __forceinline__ void stf<bf16>(bf16* p, float v){ *p = __float2bfloat16(v); }

template<typename T> struct dtag;
template<> struct dtag<float>{ static constexpr int v = 0; };
template<> struct dtag<bf16>{ static constexpr int v = 1; };

__device__ __forceinline__ f32x4 MF(s16x8 a, s16x8 b, f32x4 c){
    return __builtin_amdgcn_mfma_f32_16x16x32_bf16(a, b, c, 0, 0, 0);
}
// 8 consecutive fp32 weights -> bf16x8 fragment
__device__ __forceinline__ s16x8 wfrag8(const float* p){
    float4 a = *(const float4*)p;
    float4 c = *(const float4*)(p + 4);
    s16x8 r;
    r[0] = (short)fbits(a.x); r[1] = (short)fbits(a.y);
    r[2] = (short)fbits(a.z); r[3] = (short)fbits(a.w);
    r[4] = (short)fbits(c.x); r[5] = (short)fbits(c.y);
    r[6] = (short)fbits(c.z); r[7] = (short)fbits(c.w);
    return r;
}

// ---------------- dtype detector (fp32 low-mantissa halves decode huge/NaN) ----------------
__global__ void k_detect(const unsigned short* __restrict__ raw, int* __restrict__ flag)
{
    int t = threadIdx.x;  // 64 threads
    int bad = 0;
    for (int k = 0; k < 8; ++k) {
        unsigned short u = raw[2 * (t + 64 * k)];
        float v = __uint_as_float(((unsigned int)u) << 16);
        if (!(fabsf(v) < 1e6f)) bad = 1;
    }
    int anybad = __any(bad);
    if (t == 0) *flag = anybad ? 0 : 1;
}

// ---------------- weights -> fp32 in ws, zero SCA sums ----------------
template<typename T>
__global__ void k_prep(const T* __restrict__ w1, const T* __restrict__ b1,
                       const T* __restrict__ w3, const T* __restrict__ b3,
                       const T* __restrict__ wsc, const T* __restrict__ bsc_,
                       const T* __restrict__ w4, const T* __restrict__ b4,
                       const T* __restrict__ w5, const T* __restrict__ b5,
                       const T* __restrict__ n1w, const T* __restrict__ n1b,
                       const T* __restrict__ n2w, const T* __restrict__ n2b,
                       const T* __restrict__ bet, const T* __restrict__ gam,
                       float* __restrict__ wsf, const int* __restrict__ flag)
{
    if (*flag != dtag<T>::v) return;
    int t = threadIdx.x;
    for (int i = t; i < 2048; i += 256) wsf[OW1 + i] = ldf<T>(w1 + i);
    for (int i = t; i < 64;   i += 256) wsf[OB1 + i] = ldf<T>(b1 + i);
    for (int i = t; i < 1024; i += 256) wsf[OW3 + i] = ldf<T>(w3 + i);
    for (int i = t; i < 32;   i += 256) wsf[OB3 + i] = ldf<T>(b3 + i);
    for (int i = t; i < 1024; i += 256) wsf[OWS + i] = ldf<T>(wsc + i);
    for (int i = t; i < 32;   i += 256) wsf[OBS + i] = ldf<T>(bsc_ + i);
    for (int i = t; i < 2048; i += 256) wsf[OW4 + i] = ldf<T>(w4 + i);
    for (int i = t; i < 64;   i += 256) wsf[OB4 + i] = ldf<T>(b4 + i);
    for (int i = t; i < 1024; i += 256) wsf[OW5 + i] = ldf<T>(w5 + i);
    for (int i = t; i < 32;   i += 256) wsf[OB5 + i] = ldf<T>(b5 + i);
    for (int i = t; i < 32;   i += 256) wsf[ON1W + i] = ldf<T>(n1w + i);
    for (int i = t; i < 32;   i += 256) wsf[ON1B + i] = ldf<T>(n1b + i);
    for (int i = t; i < 32;   i += 256) wsf[ON2W + i] = ldf<T>(n2w + i);
    for (int i = t; i < 32;   i += 256) wsf[ON2B + i] = ldf<T>(n2b + i);
    for (int i = t; i < 32;   i += 256) wsf[OBETA + i] = ldf<T>(bet + i);
    for (int i = t; i < 32;   i += 256) wsf[OGAMMA + i] = ldf<T>(gam + i);
    for (int i = t; i < 128;  i += 256) wsf[OSUMS + i] = 0.f;
}

// ---------------- cw2 -> fp32 copy (vectorized, single kernel, flag branch) ----------------
__global__ void k_cwf(const void* __restrict__ cw, float4* __restrict__ cwf4,
                      const int* __restrict__ flag)
{
    int i4 = blockIdx.x * 256 + threadIdx.x;
    if (*flag == 0) {
        cwf4[i4] = ((const float4*)cw)[i4];
    } else {
        const ushort4* p = (const ushort4*)cw;
        ushort4 v = p[i4];
        cwf4[i4] = make_float4(bfu(v.x), bfu(v.y), bfu(v.z), bfu(v.w));
    }
}

// ---------------- zero the padded borders of t1 (stride-272 layout) ----------------
__global__ void k_zpad(unsigned short* __restrict__ t1u)
{
    unsigned short* pl = t1u + (size_t)blockIdx.x * TPL_;   // 256 planes
    int t = threadIdx.x;
    for (int i = t; i < 258; i += 256) {
        pl[i] = 0;
        pl[257 * TRS_ + i] = 0;
    }
    pl[(t + 1) * TRS_] = 0;
    pl[(t + 1) * TRS_ + 257] = 0;
}

// ---------------- LayerNorm2d + conv1 (32->64), writes padded t1 ----------------
template<typename T>
__device__ __forceinline__ void ln1_body(const T* __restrict__ inp,
        const float* __restrict__ wsf, bf16* __restrict__ t1p)
{
    int tid = blockIdx.x * 256 + threadIdx.x;   // 0 .. B*P-1
    int b = tid >> 16;
    int p = tid & 65535;
    int h = p >> 8, w = p & 255;
    const T* ip = inp + (size_t)b * C_ * P_ + p;
    float v[C_];
    float m = 0.f;
    #pragma unroll
    for (int ch = 0; ch < C_; ++ch) { v[ch] = ldf<T>(ip + ch * P_); m += v[ch]; }
    m *= (1.f / C_);
    float var = 0.f;
    #pragma unroll
    for (int ch = 0; ch < C_; ++ch) { float d = v[ch] - m; var += d * d; }
    var *= (1.f / C_);
    float inv = rsqrtf(var + 1e-6f);
    #pragma unroll
    for (int ch = 0; ch < C_; ++ch)
        v[ch] = (v[ch] - m) * inv * wsf[ON1W + ch] + wsf[ON1B + ch];

    bf16* op = t1p + (size_t)(b * DW_) * TPL_ + (h + 1) * TRS_ + (w + 1);
    #pragma unroll 4
    for (int o = 0; o < DW_; ++o) {
        float acc = wsf[OB1 + o];
        #pragma unroll
        for (int ch = 0; ch < C_; ++ch) acc += v[ch] * wsf[OW1 + o * C_ + ch];
        op[(size_t)o * TPL_] = f2b(acc);
    }
}

__global__ __launch_bounds__(256) void k_ln1_conv1(const void* __restrict__ inp,
        const float* __restrict__ wsf, bf16* __restrict__ t1p,
        const int* __restrict__ flag)
{
    if (*flag == 0) ln1_body<float>((const float*)inp, wsf, t1p);
    else            ln1_body<bf16>((const bf16*)inp, wsf, t1p);
}

// ------ DDF v4: 8 px per lane, vectorized t1 row loads, per-cp LDS filter slice ------
#define G_ 4
__global__ __launch_bounds__(256, 4) void k_ddf(const unsigned short* __restrict__ t1u,
        const float* __restrict__ cwf, bf16* __restrict__ g, float* __restrict__ sums)
{
    __shared__ float CWs[4320];   // [2G ch][9 tap][6 rows][10 cols] = 17280 B

    int bid = blockIdx.x;         // 1024
    int tile = bid & 31;          // 8 row-tiles x 4 col-tiles
    int cg  = (bid >> 5) & 7;     // 8 cp-groups of G_=4
    int b   = bid >> 8;           // 4
    int th = tile >> 2, tw = tile & 3;
    int cellh0 = th * 4;          // 4 cell rows per block
    int cellw0 = tw * 8;          // 8 cell cols per block
    int cp0 = cg * G_;

    {
        const float* cb = cwf + (size_t)b * (DW_ * 9 * 1024);
        for (int it = 0; it < 17; ++it) {
            int idx = it * 256 + threadIdx.x;
            if (idx < 4320) {
                int cc  = idx % 10;
                int t2  = idx / 10;
                int rr  = t2 % 6;
                int t3  = t2 / 6;
                int tap = t3 % 9;
                int chl = t3 / 9;
                int ch = (chl < G_) ? (cp0 + chl) : (C_ + cp0 + chl - G_);
                int cr = cellh0 - 1 + rr; cr = cr < 0 ? 0 : (cr > 31 ? 31 : cr);
                int cw = cellw0 - 1 + cc; cw = cw < 0 ? 0 : (cw > 31 ? 31 : cw);
                CWs[idx] = cb[ch * 9216 + tap * 1024 + cr * SRC_ + cw];
            }
        }
    }
    __syncthreads();

    int lane = threadIdx.x & 63, wid = threadIdx.x >> 6;
    int k = lane >> 3, r = lane & 7;
    int cellh = cellh0 + wid;
    int h = cellh * 8 + r;
    int w = (cellw0 + k) * 8;

    int rsel = r >> 2;
    float fh = rsel ? ((float)r * 0.125f - 0.4375f) : ((float)r * 0.125f + 0.5625f);
    float gh = 1.f - fh;
    int rr0k = (wid + rsel) * 10 + k;

    const unsigned short* tb = t1u + (size_t)(b * DW_) * TPL_ + (size_t)h * TRS_ + w;
    bf16* gp = g + (size_t)(b * C_) * P_ + h * 256 + w;

    for (int l = 0; l < G_; ++l) {
        int cp = cp0 + l;
        const unsigned short* pl1 = tb + (size_t)cp * TPL_;
        const unsigned short* pl2 = pl1 + (size_t)C_ * TPL_;
        const float* q1 = CWs + l * 540;
        const float* q2 = CWs + (G_ + l) * 540;

        float acc1[8], acc2[8];
        #pragma unroll
        for (int pass = 0; pass < 2; ++pass) {
            const unsigned short* pl = pass ? pl2 : pl1;
            const float* q = pass ? q2 : q1;
            float* acc = pass ? acc2 : acc1;

            u16x8 v8[3];
            unsigned int ve[3];
            #pragma unroll
            for (int i = 0; i < 3; ++i) {
                const unsigned short* rp = pl + i * TRS_;
                v8[i] = *(const u16x8*)rp;
                ve[i] = *(const unsigned int*)(rp + 8);
            }
            float S00[8], S01[8], S10[8], S11[8];
            #pragma unroll
            for (int c = 0; c < 8; ++c) { S00[c]=0.f; S01[c]=0.f; S10[c]=0.f; S11[c]=0.f; }
            #pragma unroll
            for (int i = 0; i < 3; ++i) {
                float p[10];
                #pragma unroll
                for (int j = 0; j < 8; ++j) p[j] = bfu((unsigned short)v8[i][j]);
                p[8] = bfu((unsigned short)(ve[i] & 0xFFFFu));
                p[9] = bfu((unsigned short)(ve[i] >> 16));
                #pragma unroll
                for (int j = 0; j < 3; ++j) {
                    const float* qb = q + (i * 3 + j) * 60 + rr0k;
                    float w00 = qb[0],  w01 = qb[1],  w02 = qb[2];
                    float w10 = qb[10], w11 = qb[11], w12 = qb[12];
                    #pragma unroll
                    for (int c = 0; c < 8; ++c) {
                        float pv = p[c + j];
                        S00[c] += pv * ((c < 4) ? w00 : w01);
                        S01[c] += pv * ((c < 4) ? w01 : w02);
                        S10[c] += pv * ((c < 4) ? w10 : w11);
                        S11[c] += pv * ((c < 4) ? w11 : w12);
                    }
                }
            }
            const float fwt[8] = {0.5625f, 0.6875f, 0.8125f, 0.9375f,
                                  0.0625f, 0.1875f, 0.3125f, 0.4375f};
            #pragma unroll
            for (int c = 0; c < 8; ++c) {
                float fw = fwt[c], gw = 1.f - fw;
                acc[c] = gh * (gw * S00[c] + fw * S01[c]) + fh * (gw * S10[c] + fw * S11[c]);
            }
        }

        u16x8 ov;
        float s = 0.f;
        #pragma unroll
        for (int c = 0; c < 8; ++c) {
            float gv = acc1[c] * acc2[c];
            s += gv;
            bf16 bv = f2b(gv);
            ov[c] = *reinterpret_cast<unsigned short*>(&bv);
        }
        *(u16x8*)(gp + (size_t)cp * P_) = ov;

        #pragma unroll
        for (int off = 32; off >= 1; off >>= 1) s += __shfl_xor(s, off, 64);
        if (lane == 0) atomicAdd(&sums[b * C_ + cp], s);
    }
}

// ---------------- SCA vector: s = sca_w @ mean + sca_b ----------------
__global__ void k_sca(float* __restrict__ wsf)
{
    int t = threadIdx.x;            // 128 threads
    int b = t >> 5, o = t & 31;
    float acc = wsf[OBS + o];
    #pragma unroll
    for (int ch = 0; ch < C_; ++ch)
        acc += wsf[OWS + o * C_ + ch] * (wsf[OSUMS + b * C_ + ch] * (1.f / (float)P_));
    wsf[OSVEC + b * C_ + o] = acc;
}

// ------- tail v2 (MFMA): scale, conv3, +beta, LN2, conv4, gate, conv5, out -------
// Block = 256 px, 4 waves x 64 px. A-operand = weights (och rows, k-contig in wsf),
// B-operand = activations staged [px][32ch] bf16 in LDS (k-contig per px row).
// D layout: och = (lane>>4)*4 + reg (+16*mtile), px = n0 + (lane&15).
// LN2 = 8 in-lane adds + shfl_xor(16,32). Gate = same-lane a4[m]*a4[m+2].
// yn/u transposes are wave-private LDS round-trips over the x region.
#define XSTR_ 32   // shorts per xsh row
#define ISTR_ 33   // floats per ipsh row (pad to kill b32 bank conflicts)

template<typename T>
__device__ __forceinline__ void tail_body(const T* __restrict__ inp,
        const bf16* __restrict__ g, const float* __restrict__ wsf,
        T* __restrict__ out, short* __restrict__ xsh, float* __restrict__ ipsh)
{
    const int t = threadIdx.x;
    const int b = blockIdx.x >> 8;
    const int p0 = (blockIdx.x & 255) << 8;

    // ---- stage: x = g*svec (bf16) -> xsh[px][32]; inp (fp32) -> ipsh[px][33] ----
    {
        float sv[32];
        #pragma unroll
        for (int q = 0; q < 8; ++q) {
            float4 v = *(const float4*)(wsf + OSVEC + b * 32 + q * 4);
            sv[4*q+0] = v.x; sv[4*q+1] = v.y; sv[4*q+2] = v.z; sv[4*q+3] = v.w;
        }
        const unsigned short* gp = (const unsigned short*)g + (size_t)(b * C_) * P_ + p0 + t;
        unsigned short row[32];
        #pragma unroll
        for (int ch = 0; ch < C_; ++ch)
            row[ch] = fbits(bfu(gp[(size_t)ch * P_]) * sv[ch]);
        u16x8* xr = (u16x8*)(xsh + t * XSTR_);
        #pragma unroll
        for (int qq = 0; qq < 4; ++qq) {
            u16x8 vv;
            #pragma unroll
            for (int j = 0; j < 8; ++j) vv[j] = row[qq * 8 + j];
            xr[qq] = vv;
        }
        const T* ip = inp + (size_t)(b * C_) * P_ + p0 + t;
        float* ir = ipsh + t * ISTR_;
        #pragma unroll
        for (int ch = 0; ch < C_; ++ch)
            ir[ch] = ldf<T>(ip + (size_t)ch * P_);
    }
    __syncthreads();

    const int lane = t & 63, wv = t >> 6;
    const int l15 = lane & 15, l4 = lane >> 4;
    const int wp0 = wv * 64;          // wave-private px range [wp0, wp0+64)

    // weight A-fragments (loaded once, converted fp32->bf16)
    s16x8 w3f[2], w4f[4];
    #pragma unroll
    for (int m = 0; m < 2; ++m) w3f[m] = wfrag8(wsf + OW3 + (m * 16 + l15) * 32 + l4 * 8);
    #pragma unroll
    for (int m = 0; m < 4; ++m) w4f[m] = wfrag8(wsf + OW4 + (m * 16 + l15) * 32 + l4 * 8);

    // ---- conv3 + beta residual -> y (fp32, 32 VGPR) ----
    f32x4 y[2][4];
    {
        f32x4 b3v[2], btv[2];
        #pragma unroll
        for (int m = 0; m < 2; ++m) {
            b3v[m] = *(const f32x4*)(wsf + OB3   + m * 16 + l4 * 4);
            btv[m] = *(const f32x4*)(wsf + OBETA + m * 16 + l4 * 4);
        }
        #pragma unroll
        for (int tn = 0; tn < 4; ++tn) {
            int px = wp0 + tn * 16 + l15;
            s16x8 xb = *(const s16x8*)(xsh + px * XSTR_ + l4 * 8);
            const float* irr = ipsh + px * ISTR_ + l4 * 4;
            #pragma unroll
            for (int m = 0; m < 2; ++m) {
                f32x4 acc = MF(w3f[m], xb, b3v[m]);   // bias-seeded
                f32x4 yy;
                #pragma unroll
                for (int i = 0; i < 4; ++i)
                    yy[i] = irr[m * 16 + i] + acc[i] * btv[m][i];
                y[m][tn] = yy;
            }
        }
    }

    // ---- LN2 -> yn (bf16) written back over x region (wave-private rows) ----
    {
        f32x4 nwv[2], nbv[2];
        #pragma unroll
        for (int m = 0; m < 2; ++m) {
            nwv[m] = *(const f32x4*)(wsf + ON2W + m * 16 + l4 * 4);
            nbv[m] = *(const f32x4*)(wsf + ON2B + m * 16 + l4 * 4);
        }
        #pragma unroll
        for (int tn = 0; tn < 4; ++tn) {
            float s = 0.f;
            #pragma unroll
            for (int m = 0; m < 2; ++m)
                #pragma unroll
                for (int i = 0; i < 4; ++i) s += y[m][tn][i];
            s += __shfl_xor(s, 16);
            s += __shfl_xor(s, 32);
            float mean = s * (1.f / 32.f);
            float q = 0.f;
            #pragma unroll
            for (int m = 0; m < 2; ++m)
                #pragma unroll
                for (int i = 0; i < 4; ++i) { float d = y[m][tn][i] - mean; q += d * d; }
            q += __shfl_xor(q, 16);
            q += __shfl_xor(q, 32);
            float inv = rsqrtf(q * (1.f / 32.f) + 1e-6f);
            int px = wp0 + tn * 16 + l15;
            #pragma unroll
            for (int m = 0; m < 2; ++m) {
                us16x4 pk;
                #pragma unroll
                for (int i = 0; i < 4; ++i)
                    pk[i] = fbits((y[m][tn][i] - mean) * inv * nwv[m][i] + nbv[m][i]);
                *(us16x4*)(xsh + px * XSTR_ + m * 16 + l4 * 4) = pk;
            }
        }
    }

    // ---- conv4 (64ch) + SimpleGate -> u (bf16) over same rows ----
    {
        f32x4 b4v[4];
        #pragma unroll
        for (int m = 0; m < 4; ++m)
            b4v[m] = *(const f32x4*)(wsf + OB4 + m * 16 + l4 * 4);
        s16x8 yb[4];
        #pragma unroll
        for (int tn = 0; tn < 4; ++tn)
            yb[tn] = *(const s16x8*)(xsh + (wp0 + tn * 16 + l15) * XSTR_ + l4 * 8);
        #pragma unroll
        for (int tn = 0; tn < 4; ++tn) {
            f32x4 a4[4];
            #pragma unroll
            for (int m = 0; m < 4; ++m) a4[m] = MF(w4f[m], yb[tn], b4v[m]);
            int px = wp0 + tn * 16 + l15;
            #pragma unroll
            for (int m = 0; m < 2; ++m) {
                us16x4 pk;
                #pragma unroll
                for (int i = 0; i < 4; ++i) pk[i] = fbits(a4[m][i] * a4[m + 2][i]);
                *(us16x4*)(xsh + px * XSTR_ + m * 16 + l4 * 4) = pk;
            }
        }
    }

    // ---- conv5 + gamma residual -> out ----
    {
        s16x8 w5f[2];
        #pragma unroll
        for (int m = 0; m < 2; ++m) w5f[m] = wfrag8(wsf + OW5 + (m * 16 + l15) * 32 + l4 * 8);
        f32x4 b5v[2], gmv[2];
        #pragma unroll
        for (int m = 0; m < 2; ++m) {
            b5v[m] = *(const f32x4*)(wsf + OB5    + m * 16 + l4 * 4);
            gmv[m] = *(const f32x4*)(wsf + OGAMMA + m * 16 + l4 * 4);
        }
        s16x8 ub[4];
        #pragma unroll
        for (int tn = 0; tn < 4; ++tn)
            ub[tn] = *(const s16x8*)(xsh + (wp0 + tn * 16 + l15) * XSTR_ + l4 * 8);
        #pragma unroll
        for (int tn = 0; tn < 4; ++tn) {
            int px = p0 + wp0 + tn * 16 + l15;
            #pragma unroll
            for (int m = 0; m < 2; ++m) {
                f32x4 acc = MF(w5f[m], ub[tn], b5v[m]);
                #pragma unroll
                for (int i = 0; i < 4; ++i) {
                    int och = m * 16 + l4 * 4 + i;
                    stf<T>(out + (size_t)(b * C_ + och) * P_ + px,
                           y[m][tn][i] + acc[i] * gmv[m][i]);
                }
            }
        }
    }
}

__global__ __launch_bounds__(256, 3) void k_tail(const void* __restrict__ inp,
        const bf16* __restrict__ g, const float* __restrict__ wsf,
        void* __restrict__ out, const int* __restrict__ flag)
{
    __shared__ short xsh[256 * XSTR_];   // 16384 B
    __shared__ float ipsh[256 * ISTR_];  // 33792 B
    if (*flag == 0) tail_body<float>((const float*)inp, g, wsf, (float*)out, xsh, ipsh);
    else            tail_body<bf16>((const bf16*)inp, g, wsf, (bf16*)out, xsh, ipsh);
}

extern "C" void kernel_launch(void* const* d_in, const int* in_sizes, int n_in,
                              void* d_out, int out_size, void* d_ws, size_t ws_size,
                              hipStream_t stream)
{
    float* wsf = (float*)d_ws;
    char* wsb = (char*)d_ws;
    float* cwf = (float*)(wsb + CWF_BOFF);
    bf16* t1p = (bf16*)(wsb + T1_BOFF);
    bf16* g   = (bf16*)(wsb + G_BOFF);
    int* flag = (int*)(wsf + OFLAG);

    k_detect<<<1, 64, 0, stream>>>((const unsigned short*)d_in[0], flag);

    int nblk = (B_ * P_) / 256;   // 1024

    k_prep<float><<<1, 256, 0, stream>>>(
        (const float*)d_in[2], (const float*)d_in[3], (const float*)d_in[4],
        (const float*)d_in[5], (const float*)d_in[6], (const float*)d_in[7],
        (const float*)d_in[8], (const float*)d_in[9], (const float*)d_in[10],
        (const float*)d_in[11], (const float*)d_in[12], (const float*)d_in[13],
        (const float*)d_in[14], (const float*)d_in[15], (const float*)d_in[16],
        (const float*)d_in[17], wsf, flag);
    k_prep<bf16><<<1, 256, 0, stream>>>(
        (const bf16*)d_in[2], (const bf16*)d_in[3], (const bf16*)d_in[4],
        (const bf16*)d_in[5], (const bf16*)d_in[6], (const bf16*)d_in[7],
        (const bf16*)d_in[8], (const bf16*)d_in[9], (const bf16*)d_in[10],
        (const bf16*)d_in[11], (const bf16*)d_in[12], (const bf16*)d_in[13],
        (const bf16*)d_in[14], (const bf16*)d_in[15], (const bf16*)d_in[16],
        (const bf16*)d_in[17], wsf, flag);

    k_cwf<<<2304, 256, 0, stream>>>(d_in[1], (float4*)cwf, flag);

    k_zpad<<<256, 256, 0, stream>>>((unsigned short*)t1p);

    k_ln1_conv1<<<nblk, 256, 0, stream>>>(d_in[0], wsf, t1p, flag);

    k_ddf<<<1024, 256, 0, stream>>>((const unsigned short*)t1p, cwf, g, wsf + OSUMS);

    k_sca<<<1, 128, 0, stream>>>(wsf);

    k_tail<<<nblk, 256, 0, stream>>>(d_in[0], g, wsf, d_out, flag);
}